// Round 2
// baseline (2620.392 us; speedup 1.0000x reference)
//
#include <hip/hip_runtime.h>
#include <hip/hip_bf16.h>
#include <math.h>

#define B_  4
#define T_  2048
#define C_  2048      // N_EMBD
#define F_  3072      // 3*N_LATENT
#define NL_ 1024      // N_LATENT
#define H_  16
#define D_  64
#define DH_ 32        // half head dim

typedef unsigned int  uint;
typedef unsigned short ushort;
typedef __bf16 bf16x8 __attribute__((ext_vector_type(8)));
typedef float  f32x4  __attribute__((ext_vector_type(4)));

__device__ __forceinline__ void fma4(float4& acc, float a, const float4& b) {
    acc.x = fmaf(a, b.x, acc.x);
    acc.y = fmaf(a, b.y, acc.y);
    acc.z = fmaf(a, b.z, acc.z);
    acc.w = fmaf(a, b.w, acc.w);
}

// round-to-nearest-even f32 -> bf16 (finite inputs)
__device__ __forceinline__ ushort f2bf(float f) {
    uint u = __float_as_uint(f);
    u += 0x7FFFu + ((u >> 16) & 1u);
    return (ushort)(u >> 16);
}
__device__ __forceinline__ float bf2f(ushort h) {
    return __uint_as_float(((uint)h) << 16);
}

// ---------------------------------------------------------------------------
// RoPE tables: cos/sin[t][i], i in [0,32).
// ---------------------------------------------------------------------------
__global__ void rope_tables_k(float* __restrict__ cosT, float* __restrict__ sinT) {
    int idx = blockIdx.x * 256 + threadIdx.x;
    if (idx >= T_ * DH_) return;
    int t = idx >> 5;
    int i = idx & 31;
    float inv = (float)pow(10000.0, -(double)(2 * i) / 64.0);
    float ang = (float)t * inv;
    cosT[idx] = cosf(ang);
    sinT[idx] = sinf(ang);
}

// ---------------------------------------------------------------------------
// Pack fp32 matrix S[R][K] (row-major) into split-bf16 fragment-major tiles.
// Tile (rt,kt) = 8192 bf16: hi[4096] then lo[4096].
// chunk ch in [0,512): row = rt*128 + (ch>>6)*16 + (ch&15),
//                      k   = kt*32 + ((ch>>4)&3)*8 + j,  j in [0,8)
// value at P[tileBase + ch*8 + j]  (lo at +4096).
// This is exactly the mfma_f32_16x16x32_bf16 A/B fragment order, so the GEMM
// stages tiles as LINEAR 16KB copies via global_load_lds.
// ---------------------------------------------------------------------------
__global__ __launch_bounds__(256) void pack_split_k(const float* __restrict__ S,
                                                    ushort* __restrict__ P,
                                                    int K, int Ktiles) {
    __shared__ float Ls[128][36];
    const int t  = threadIdx.x;
    const int kt = blockIdx.x;
    const int rt = blockIdx.y;

    // phase 1: coalesced load of the 128x32 fp32 tile
#pragma unroll
    for (int i = 0; i < 4; ++i) {
        const int f   = t + i * 256;       // float4 slot 0..1023
        const int row = f >> 3;
        const int kc  = (f & 7) * 4;
        const float4 v = *(const float4*)(S + (size_t)(rt * 128 + row) * K + kt * 32 + kc);
        *(float4*)&Ls[row][kc] = v;
    }
    __syncthreads();

    const size_t tb = ((size_t)rt * Ktiles + kt) * 8192;
#pragma unroll
    for (int c = 0; c < 2; ++c) {
        const int ch  = t + c * 256;
        const int row = ((ch >> 6) << 4) + (ch & 15);
        const int k0  = ((ch >> 4) & 3) * 8;
        uint hi[4], lo[4];
#pragma unroll
        for (int jj = 0; jj < 4; ++jj) {
            const float v0 = Ls[row][k0 + jj * 2];
            const float v1 = Ls[row][k0 + jj * 2 + 1];
            const ushort h0 = f2bf(v0), h1 = f2bf(v1);
            const ushort l0 = f2bf(v0 - bf2f(h0)), l1 = f2bf(v1 - bf2f(h1));
            hi[jj] = (uint)h0 | ((uint)h1 << 16);
            lo[jj] = (uint)l0 | ((uint)l1 << 16);
        }
        *(uint4*)(P + tb + (size_t)ch * 8)        = make_uint4(hi[0], hi[1], hi[2], hi[3]);
        *(uint4*)(P + tb + 4096 + (size_t)ch * 8) = make_uint4(lo[0], lo[1], lo[2], lo[3]);
    }
}

// ---------------------------------------------------------------------------
// bf16x3 MFMA GEMM on packed tiles: C[M][N] fp32 = A * B^T (both packed).
// 128x128 tile, BK=32, 4 waves; per wave 4x4 fragments of 16x16.
// 3 MFMA per fragment pair: ah*bh + ah*bl + al*bh (al*bl dropped, ~2^-18).
// ---------------------------------------------------------------------------
__global__ __launch_bounds__(256, 2) void gemm_bf16x3(const ushort* __restrict__ Ap,
                                                      const ushort* __restrict__ Bp,
                                                      float* __restrict__ Cc,
                                                      int Mt, int Nt, int Kt) {
    __shared__ ushort Al[8192];   // hi 4096 + lo 4096
    __shared__ ushort Bl[8192];

    const int t    = threadIdx.x;
    const int lane = t & 63;
    const int w    = t >> 6;
    const int wr   = w >> 1, wc = w & 1;
    const int bn   = blockIdx.x, bm = blockIdx.y;

    const ushort* Atiles = Ap + (size_t)bm * Kt * 8192;
    const ushort* Btiles = Bp + (size_t)bn * Kt * 8192;

    // wave staging assignment (uniform per wave): waves 0,1 -> A; 2,3 -> B
    const ushort* gbase;
    ushort*       lbase;
    if (w < 2) { gbase = Atiles + w * 4096;       lbase = Al + w * 4096; }
    else       { gbase = Btiles + (w - 2) * 4096; lbase = Bl + (w - 2) * 4096; }

    f32x4 acc[4][4];
#pragma unroll
    for (int i = 0; i < 4; ++i)
#pragma unroll
        for (int j = 0; j < 4; ++j)
            acc[i][j] = (f32x4){0.f, 0.f, 0.f, 0.f};

    for (int kt = 0; kt < Kt; ++kt) {
        const ushort* gsrc = gbase + (size_t)kt * 8192;
#pragma unroll
        for (int i = 0; i < 8; ++i) {
            __builtin_amdgcn_global_load_lds(
                (const __attribute__((address_space(1))) uint*)(gsrc + i * 512 + lane * 8),
                (__attribute__((address_space(3))) uint*)(lbase + i * 512),
                16, 0, 0);
        }
        __syncthreads();   // drains global_load_lds (compiler emits vmcnt(0))

        bf16x8 ah[4], al4[4], bh[4], bl4[4];
#pragma unroll
        for (int i = 0; i < 4; ++i) {
            const int rg = wr * 4 + i;
            ah[i]  = *(const bf16x8*)&Al[rg * 512 + lane * 8];
            al4[i] = *(const bf16x8*)&Al[4096 + rg * 512 + lane * 8];
            const int cg = wc * 4 + i;
            bh[i]  = *(const bf16x8*)&Bl[cg * 512 + lane * 8];
            bl4[i] = *(const bf16x8*)&Bl[4096 + cg * 512 + lane * 8];
        }
#pragma unroll
        for (int i = 0; i < 4; ++i)
#pragma unroll
            for (int j = 0; j < 4; ++j) {
                acc[i][j] = __builtin_amdgcn_mfma_f32_16x16x32_bf16(ah[i],  bh[j],  acc[i][j], 0, 0, 0);
                acc[i][j] = __builtin_amdgcn_mfma_f32_16x16x32_bf16(ah[i],  bl4[j], acc[i][j], 0, 0, 0);
                acc[i][j] = __builtin_amdgcn_mfma_f32_16x16x32_bf16(al4[i], bh[j],  acc[i][j], 0, 0, 0);
            }
        __syncthreads();   // fragment reads done before next stage overwrites
    }

    // epilogue: C/D layout col = lane&15, row = (lane>>4)*4 + reg  [m89-verified]
    const int N = Nt * 128;
#pragma unroll
    for (int i = 0; i < 4; ++i) {
        const int row0 = bm * 128 + wr * 64 + i * 16 + (lane >> 4) * 4;
#pragma unroll
        for (int j = 0; j < 4; ++j) {
            const int col = bn * 128 + wc * 64 + j * 16 + (lane & 15);
#pragma unroll
            for (int r = 0; r < 4; ++r)
                Cc[(size_t)(row0 + r) * N + col] = acc[i][j][r];
        }
    }
}

// ---------------------------------------------------------------------------
// fp32 NT GEMM fallback (used only if ws_size is too small for packing).
// ---------------------------------------------------------------------------
__global__ __launch_bounds__(256) void gemm_nt(const float* __restrict__ A,
                                               const float* __restrict__ Bw,
                                               float* __restrict__ Cc,
                                               int M, int N, int K) {
    __shared__ float As[16][128];
    __shared__ float Bs[16][128];

    const int t  = threadIdx.x;
    const int tx = t & 15;
    const int ty = t >> 4;
    const int bm = blockIdx.y * 128;
    const int bn = blockIdx.x * 128;

    const int lr = t >> 1;
    const int lk = (t & 1) * 8;

    const float* Ap = A  + (size_t)(bm + lr) * K + lk;
    const float* Bp = Bw + (size_t)(bn + lr) * K + lk;

    float4 acc[2][4][2];
#pragma unroll
    for (int rh = 0; rh < 2; ++rh)
#pragma unroll
        for (int i = 0; i < 4; ++i)
#pragma unroll
            for (int ch = 0; ch < 2; ++ch)
                acc[rh][i][ch] = make_float4(0.f, 0.f, 0.f, 0.f);

    for (int kt = 0; kt < K; kt += 16) {
        const float4 a0 = *(const float4*)(Ap + kt);
        const float4 a1 = *(const float4*)(Ap + kt + 4);
        const float4 b0 = *(const float4*)(Bp + kt);
        const float4 b1 = *(const float4*)(Bp + kt + 4);
        __syncthreads();
        As[lk + 0][lr] = a0.x; As[lk + 1][lr] = a0.y;
        As[lk + 2][lr] = a0.z; As[lk + 3][lr] = a0.w;
        As[lk + 4][lr] = a1.x; As[lk + 5][lr] = a1.y;
        As[lk + 6][lr] = a1.z; As[lk + 7][lr] = a1.w;
        Bs[lk + 0][lr] = b0.x; Bs[lk + 1][lr] = b0.y;
        Bs[lk + 2][lr] = b0.z; Bs[lk + 3][lr] = b0.w;
        Bs[lk + 4][lr] = b1.x; Bs[lk + 5][lr] = b1.y;
        Bs[lk + 6][lr] = b1.z; Bs[lk + 7][lr] = b1.w;
        __syncthreads();

#pragma unroll
        for (int kk = 0; kk < 16; ++kk) {
            const float4 av0 = *(const float4*)&As[kk][ty * 4];
            const float4 av1 = *(const float4*)&As[kk][64 + ty * 4];
            const float4 bv0 = *(const float4*)&Bs[kk][tx * 4];
            const float4 bv1 = *(const float4*)&Bs[kk][64 + tx * 4];
            fma4(acc[0][0][0], av0.x, bv0); fma4(acc[0][0][1], av0.x, bv1);
            fma4(acc[0][1][0], av0.y, bv0); fma4(acc[0][1][1], av0.y, bv1);
            fma4(acc[0][2][0], av0.z, bv0); fma4(acc[0][2][1], av0.z, bv1);
            fma4(acc[0][3][0], av0.w, bv0); fma4(acc[0][3][1], av0.w, bv1);
            fma4(acc[1][0][0], av1.x, bv0); fma4(acc[1][0][1], av1.x, bv1);
            fma4(acc[1][1][0], av1.y, bv0); fma4(acc[1][1][1], av1.y, bv1);
            fma4(acc[1][2][0], av1.z, bv0); fma4(acc[1][2][1], av1.z, bv1);
            fma4(acc[1][3][0], av1.w, bv0); fma4(acc[1][3][1], av1.w, bv1);
        }
    }

#pragma unroll
    for (int rh = 0; rh < 2; ++rh)
#pragma unroll
        for (int i = 0; i < 4; ++i) {
            const size_t row = (size_t)(bm + rh * 64 + ty * 4 + i);
            float* cp = Cc + row * N + bn + tx * 4;
            *(float4*)cp        = acc[rh][i][0];
            *(float4*)(cp + 64) = acc[rh][i][1];
        }
}

// ---------------------------------------------------------------------------
// Fused RMSNorm + RoPE for q and k rows (in place).
// ---------------------------------------------------------------------------
__global__ __launch_bounds__(256) void rmsnorm_rope_k(float* __restrict__ qkv,
                                                      const float* __restrict__ cosT,
                                                      const float* __restrict__ sinT) {
    const int tid  = threadIdx.x;
    const int lane = tid & 63;
    const int rsub = tid >> 6;
    const long rid = (long)blockIdx.x * 4 + rsub;
    const int bt  = (int)(rid >> 5);
    const int rem = (int)(rid & 31);
    const int h   = rem >> 1;
    const int qk  = rem & 1;

    float* row = qkv + (size_t)bt * F_ + qk * NL_ + h * 64;
    float v = row[lane];

    float ss = v * v;
    ss += __shfl_xor(ss, 1);
    ss += __shfl_xor(ss, 2);
    ss += __shfl_xor(ss, 4);
    ss += __shfl_xor(ss, 8);
    ss += __shfl_xor(ss, 16);
    ss += __shfl_xor(ss, 32);
    const float r = 1.0f / sqrtf(ss * (1.0f / 64.0f) + 1e-6f);
    const float xn = v * r;

    const float other = __shfl_xor(xn, 32);
    const int  i  = lane & 31;
    const int  tt = bt & (T_ - 1);
    const float cv = cosT[tt * DH_ + i];
    const float sv = sinT[tt * DH_ + i];
    float outv;
    if (lane < 32) outv = fmaf(xn, cv,  other * sv);
    else           outv = fmaf(xn, cv, -other * sv);
    row[lane] = outv;
}

// ---------------------------------------------------------------------------
// Flash attention fp32 (unchanged from round 0; VALU-bound target for later).
// ---------------------------------------------------------------------------
__global__ __launch_bounds__(256) void attn_k(const float* __restrict__ qkv,
                                              float* __restrict__ Y) {
    __shared__ float Qt[64][68];
    __shared__ float Kt[64][68];
    __shared__ float Vs[64][64];

    const int t  = threadIdx.x;
    const int tx = t & 15;
    const int ty = t >> 4;
    const int qb = blockIdx.x;
    const int h  = blockIdx.y;
    const int b  = blockIdx.z;

    const float* base = qkv + (size_t)b * T_ * F_;

#pragma unroll
    for (int i = 0; i < 16; ++i) {
        const int idx = i * 256 + t;
        const int r = idx >> 6, d = idx & 63;
        Qt[d][r] = 0.125f * base[(size_t)(qb * 64 + r) * F_ + h * 64 + d];
    }

    float m[4], l[4];
    float4 y[4];
#pragma unroll
    for (int i = 0; i < 4; ++i) {
        m[i] = -3.0e38f; l[i] = 0.f;
        y[i] = make_float4(0.f, 0.f, 0.f, 0.f);
    }
    __syncthreads();

    for (int kt = 0; kt <= qb; ++kt) {
#pragma unroll
        for (int i = 0; i < 16; ++i) {
            const int idx = i * 256 + t;
            const int c = idx >> 6, d = idx & 63;
            const float* krow = base + (size_t)(kt * 64 + c) * F_ + NL_ + h * 64;
            Kt[d][c] = krow[d];
            Vs[c][d] = krow[NL_ + d];
        }
        __syncthreads();

        float4 s[4];
#pragma unroll
        for (int i = 0; i < 4; ++i) s[i] = make_float4(0.f, 0.f, 0.f, 0.f);
#pragma unroll
        for (int kk = 0; kk < 64; ++kk) {
            const float4 aq = *(const float4*)&Qt[kk][ty * 4];
            const float4 bk = *(const float4*)&Kt[kk][tx * 4];
            fma4(s[0], aq.x, bk);
            fma4(s[1], aq.y, bk);
            fma4(s[2], aq.z, bk);
            fma4(s[3], aq.w, bk);
        }

        if (kt == qb) {
#pragma unroll
            for (int i = 0; i < 4; ++i) {
                const int r = ty * 4 + i, c0 = tx * 4;
                if (c0 + 0 > r) s[i].x = -3.0e38f;
                if (c0 + 1 > r) s[i].y = -3.0e38f;
                if (c0 + 2 > r) s[i].z = -3.0e38f;
                if (c0 + 3 > r) s[i].w = -3.0e38f;
            }
        }

#pragma unroll
        for (int i = 0; i < 4; ++i) {
            float tm = fmaxf(fmaxf(s[i].x, s[i].y), fmaxf(s[i].z, s[i].w));
            tm = fmaxf(tm, __shfl_xor(tm, 1));
            tm = fmaxf(tm, __shfl_xor(tm, 2));
            tm = fmaxf(tm, __shfl_xor(tm, 4));
            tm = fmaxf(tm, __shfl_xor(tm, 8));
            const float nm = fmaxf(m[i], tm);
            const float co = __expf(m[i] - nm);
            s[i].x = __expf(s[i].x - nm); s[i].y = __expf(s[i].y - nm);
            s[i].z = __expf(s[i].z - nm); s[i].w = __expf(s[i].w - nm);
            float ps = s[i].x + s[i].y + s[i].z + s[i].w;
            ps += __shfl_xor(ps, 1);
            ps += __shfl_xor(ps, 2);
            ps += __shfl_xor(ps, 4);
            ps += __shfl_xor(ps, 8);
            l[i] = l[i] * co + ps;
            m[i] = nm;
            y[i].x *= co; y[i].y *= co; y[i].z *= co; y[i].w *= co;
        }

        __syncthreads();
        float (*Pl)[68] = Kt;
#pragma unroll
        for (int i = 0; i < 4; ++i)
            *(float4*)&Pl[ty * 4 + i][tx * 4] = s[i];
        __syncthreads();

#pragma unroll
        for (int j0 = 0; j0 < 16; ++j0) {
            const float4 p0 = *(const float4*)&Pl[ty * 4 + 0][j0 * 4];
            const float4 p1 = *(const float4*)&Pl[ty * 4 + 1][j0 * 4];
            const float4 p2 = *(const float4*)&Pl[ty * 4 + 2][j0 * 4];
            const float4 p3 = *(const float4*)&Pl[ty * 4 + 3][j0 * 4];
            {
                const float4 bv = *(const float4*)&Vs[j0 * 4 + 0][tx * 4];
                fma4(y[0], p0.x, bv); fma4(y[1], p1.x, bv);
                fma4(y[2], p2.x, bv); fma4(y[3], p3.x, bv);
            }
            {
                const float4 bv = *(const float4*)&Vs[j0 * 4 + 1][tx * 4];
                fma4(y[0], p0.y, bv); fma4(y[1], p1.y, bv);
                fma4(y[2], p2.y, bv); fma4(y[3], p3.y, bv);
            }
            {
                const float4 bv = *(const float4*)&Vs[j0 * 4 + 2][tx * 4];
                fma4(y[0], p0.z, bv); fma4(y[1], p1.z, bv);
                fma4(y[2], p2.z, bv); fma4(y[3], p3.z, bv);
            }
            {
                const float4 bv = *(const float4*)&Vs[j0 * 4 + 3][tx * 4];
                fma4(y[0], p0.w, bv); fma4(y[1], p1.w, bv);
                fma4(y[2], p2.w, bv); fma4(y[3], p3.w, bv);
            }
        }
        __syncthreads();
    }

#pragma unroll
    for (int i = 0; i < 4; ++i) {
        const float inv = 1.0f / l[i];
        float4 o = y[i];
        o.x *= inv; o.y *= inv; o.z *= inv; o.w *= inv;
        const int r = qb * 64 + ty * 4 + i;
        *(float4*)(Y + ((size_t)(b * T_ + r)) * NL_ + h * 64 + tx * 4) = o;
    }
}

// ---------------------------------------------------------------------------
extern "C" void kernel_launch(void* const* d_in, const int* in_sizes, int n_in,
                              void* d_out, int out_size, void* d_ws, size_t ws_size,
                              hipStream_t stream) {
    const float* x     = (const float*)d_in[0];
    const float* w_qkv = (const float*)d_in[1];
    const float* w_out = (const float*)d_in[2];
    float* out = (float*)d_out;

    const size_t M   = (size_t)B_ * T_;       // 8192
    const size_t nQKV = M * F_;               // 25.17M floats
    const size_t nY   = M * NL_;              // 8.39M floats
    const size_t nTab = (size_t)T_ * DH_;     // 65536 floats

    float* qkv  = (float*)d_ws;
    float* y    = qkv + nQKV;
    float* cosT = y + nY;
    float* sinT = cosT + nTab;
    float* wsEndF = sinT + nTab;

    // packed regions (ushort), 16B-aligned by construction
    ushort* xpack    = (ushort*)wsEndF;                          // M*C*2
    ushort* wqkvpack = xpack    + M * C_ * 2;                    // F*C*2
    ushort* ypack    = wqkvpack + (size_t)F_ * C_ * 2;           // M*NL*2
    ushort* woutpack = ypack    + M * NL_ * 2;                   // C*NL*2
    const size_t needBytes = (size_t)((char*)(woutpack + (size_t)C_ * NL_ * 2) - (char*)d_ws);

    rope_tables_k<<<(T_ * DH_ + 255) / 256, 256, 0, stream>>>(cosT, sinT);

    const bool useMfma = (ws_size >= needBytes);

    if (useMfma) {
        pack_split_k<<<dim3(C_ / 32, M / 128), 256, 0, stream>>>(x, xpack, C_, C_ / 32);
        pack_split_k<<<dim3(C_ / 32, F_ / 128), 256, 0, stream>>>(w_qkv, wqkvpack, C_, C_ / 32);
        pack_split_k<<<dim3(NL_ / 32, C_ / 128), 256, 0, stream>>>(w_out, woutpack, NL_, NL_ / 32);
        gemm_bf16x3<<<dim3(F_ / 128, M / 128), 256, 0, stream>>>(
            xpack, wqkvpack, qkv, M / 128, F_ / 128, C_ / 32);
    } else {
        gemm_nt<<<dim3(F_ / 128, M / 128), 256, 0, stream>>>(
            x, w_qkv, qkv, (int)M, F_, C_);
    }

    rmsnorm_rope_k<<<(B_ * T_ * H_ * 2) / 4, 256, 0, stream>>>(qkv, cosT, sinT);

    attn_k<<<dim3(T_ / 64, H_, B_), 256, 0, stream>>>(qkv, y);

    if (useMfma) {
        pack_split_k<<<dim3(NL_ / 32, M / 128), 256, 0, stream>>>(y, ypack, NL_, NL_ / 32);
        gemm_bf16x3<<<dim3(C_ / 128, M / 128), 256, 0, stream>>>(
            ypack, woutpack, out, M / 128, C_ / 128, NL_ / 32);
    } else {
        gemm_nt<<<dim3(C_ / 128, M / 128), 256, 0, stream>>>(
            y, w_out, out, (int)M, C_, NL_);
    }
}

// Round 5
// 1182.619 us; speedup vs baseline: 2.2158x; 2.2158x over previous
//
#include <hip/hip_runtime.h>
#include <hip/hip_bf16.h>
#include <math.h>

#define B_  4
#define T_  2048
#define C_  2048      // N_EMBD
#define F_  3072      // 3*N_LATENT
#define NL_ 1024      // N_LATENT
#define H_  16
#define D_  64
#define DH_ 32        // half head dim

typedef unsigned int  uint;
typedef unsigned short ushort;
typedef __bf16 bf16x8 __attribute__((ext_vector_type(8)));
typedef float  f32x4  __attribute__((ext_vector_type(4)));

// round-to-nearest-even f32 -> bf16 (finite inputs)
__device__ __forceinline__ ushort f2bf(float f) {
    uint u = __float_as_uint(f);
    u += 0x7FFFu + ((u >> 16) & 1u);
    return (ushort)(u >> 16);
}
__device__ __forceinline__ float bf2f(ushort h) {
    return __uint_as_float(((uint)h) << 16);
}

// split two float4 (8 elems, optional scale) into hi/lo bf16x8 fragments
__device__ __forceinline__ void split8(const float4& v0, const float4& v1,
                                       float scale, bf16x8& hi, bf16x8& lo) {
    union { ushort u[8]; bf16x8 v; } Hh, Ll;
    float vv[8] = {v0.x, v0.y, v0.z, v0.w, v1.x, v1.y, v1.z, v1.w};
#pragma unroll
    for (int j = 0; j < 8; ++j) {
        const float s = scale * vv[j];
        const ushort h = f2bf(s);
        Hh.u[j] = h;
        Ll.u[j] = f2bf(s - bf2f(h));
    }
    hi = Hh.v; lo = Ll.v;
}

// ---------------------------------------------------------------------------
// RoPE tables: cos/sin[t][i], i in [0,32).
// ---------------------------------------------------------------------------
__global__ void rope_tables_k(float* __restrict__ cosT, float* __restrict__ sinT) {
    int idx = blockIdx.x * 256 + threadIdx.x;
    if (idx >= T_ * DH_) return;
    int t = idx >> 5;
    int i = idx & 31;
    float inv = (float)pow(10000.0, -(double)(2 * i) / 64.0);
    float ang = (float)t * inv;
    cosT[idx] = cosf(ang);
    sinT[idx] = sinf(ang);
}

// ---------------------------------------------------------------------------
// Pack fp32 matrix S[R][K] (row-major) into split-bf16 fragment-major tiles.
// Tile (rt,kt) = 8192 bf16: hi[4096] then lo[4096].
// chunk ch in [0,512): row = rt*128 + (ch>>6)*16 + (ch&15),
//                      k   = kt*32 + ((ch>>4)&3)*8 + j,  j in [0,8)
// value at P[tileBase + ch*8 + j]  (lo at +4096).
// Lane `a` reading fragment for row-group rg reads chunk (rg*64 + a) ->
// linear ds_read_b128, and staging is a linear 16KB copy.
// ---------------------------------------------------------------------------
__global__ __launch_bounds__(256) void pack_split_k(const float* __restrict__ S,
                                                    ushort* __restrict__ P,
                                                    int K, int Ktiles) {
    __shared__ float Ls[128][36];
    const int t  = threadIdx.x;
    const int kt = blockIdx.x;
    const int rt = blockIdx.y;

#pragma unroll
    for (int i = 0; i < 4; ++i) {
        const int f   = t + i * 256;
        const int row = f >> 3;
        const int kc  = (f & 7) * 4;
        const float4 v = *(const float4*)(S + (size_t)(rt * 128 + row) * K + kt * 32 + kc);
        *(float4*)&Ls[row][kc] = v;
    }
    __syncthreads();

    const size_t tb = ((size_t)rt * Ktiles + kt) * 8192;
#pragma unroll
    for (int c = 0; c < 2; ++c) {
        const int ch  = t + c * 256;
        const int row = ((ch >> 6) << 4) + (ch & 15);
        const int k0  = ((ch >> 4) & 3) * 8;
        uint hi[4], lo[4];
#pragma unroll
        for (int jj = 0; jj < 4; ++jj) {
            const float v0 = Ls[row][k0 + jj * 2];
            const float v1 = Ls[row][k0 + jj * 2 + 1];
            const ushort h0 = f2bf(v0), h1 = f2bf(v1);
            const ushort l0 = f2bf(v0 - bf2f(h0)), l1 = f2bf(v1 - bf2f(h1));
            hi[jj] = (uint)h0 | ((uint)h1 << 16);
            lo[jj] = (uint)l0 | ((uint)l1 << 16);
        }
        *(uint4*)(P + tb + (size_t)ch * 8)        = make_uint4(hi[0], hi[1], hi[2], hi[3]);
        *(uint4*)(P + tb + 4096 + (size_t)ch * 8) = make_uint4(lo[0], lo[1], lo[2], lo[3]);
    }
}

// ---------------------------------------------------------------------------
// bf16x3 MFMA GEMM on packed tiles: C[M][N] fp32 = A * B^T (both packed).
// 128x128 tile, BK=32, 4 waves; per wave 4x4 fragments of 16x16.
// ---------------------------------------------------------------------------
__global__ __launch_bounds__(256, 2) void gemm_bf16x3(const ushort* __restrict__ Ap,
                                                      const ushort* __restrict__ Bp,
                                                      float* __restrict__ Cc,
                                                      int Mt, int Nt, int Kt) {
    __shared__ ushort Al[8192];   // hi 4096 + lo 4096
    __shared__ ushort Bl[8192];

    const int t    = threadIdx.x;
    const int lane = t & 63;
    const int w    = t >> 6;
    const int wr   = w >> 1, wc = w & 1;
    const int bn   = blockIdx.x, bm = blockIdx.y;

    const ushort* Atiles = Ap + (size_t)bm * Kt * 8192;
    const ushort* Btiles = Bp + (size_t)bn * Kt * 8192;

    const ushort* gbase;
    ushort*       lbase;
    if (w < 2) { gbase = Atiles + w * 4096;       lbase = Al + w * 4096; }
    else       { gbase = Btiles + (w - 2) * 4096; lbase = Bl + (w - 2) * 4096; }

    f32x4 acc[4][4];
#pragma unroll
    for (int i = 0; i < 4; ++i)
#pragma unroll
        for (int j = 0; j < 4; ++j)
            acc[i][j] = (f32x4){0.f, 0.f, 0.f, 0.f};

    for (int kt = 0; kt < Kt; ++kt) {
        const ushort* gsrc = gbase + (size_t)kt * 8192;
#pragma unroll
        for (int i = 0; i < 8; ++i) {
            __builtin_amdgcn_global_load_lds(
                (const __attribute__((address_space(1))) uint*)(gsrc + i * 512 + lane * 8),
                (__attribute__((address_space(3))) uint*)(lbase + i * 512),
                16, 0, 0);
        }
        __syncthreads();

        bf16x8 ah[4], al4[4], bh[4], bl4[4];
#pragma unroll
        for (int i = 0; i < 4; ++i) {
            const int rg = wr * 4 + i;
            ah[i]  = *(const bf16x8*)&Al[rg * 512 + lane * 8];
            al4[i] = *(const bf16x8*)&Al[4096 + rg * 512 + lane * 8];
            const int cg = wc * 4 + i;
            bh[i]  = *(const bf16x8*)&Bl[cg * 512 + lane * 8];
            bl4[i] = *(const bf16x8*)&Bl[4096 + cg * 512 + lane * 8];
        }
#pragma unroll
        for (int i = 0; i < 4; ++i)
#pragma unroll
            for (int j = 0; j < 4; ++j) {
                acc[i][j] = __builtin_amdgcn_mfma_f32_16x16x32_bf16(ah[i],  bh[j],  acc[i][j], 0, 0, 0);
                acc[i][j] = __builtin_amdgcn_mfma_f32_16x16x32_bf16(ah[i],  bl4[j], acc[i][j], 0, 0, 0);
                acc[i][j] = __builtin_amdgcn_mfma_f32_16x16x32_bf16(al4[i], bh[j],  acc[i][j], 0, 0, 0);
            }
        __syncthreads();
    }

    const int N = Nt * 128;
#pragma unroll
    for (int i = 0; i < 4; ++i) {
        const int row0 = bm * 128 + wr * 64 + i * 16 + (lane >> 4) * 4;
#pragma unroll
        for (int j = 0; j < 4; ++j) {
            const int col = bn * 128 + wc * 64 + j * 16 + (lane & 15);
#pragma unroll
            for (int r = 0; r < 4; ++r)
                Cc[(size_t)(row0 + r) * N + col] = acc[i][j][r];
        }
    }
}

// ---------------------------------------------------------------------------
// Fused RMSNorm + RoPE for q and k rows (in place).  [measured-passing r2]
// ---------------------------------------------------------------------------
__global__ __launch_bounds__(256) void rmsnorm_rope_k(float* __restrict__ qkv,
                                                      const float* __restrict__ cosT,
                                                      const float* __restrict__ sinT) {
    const int tid  = threadIdx.x;
    const int lane = tid & 63;
    const int rsub = tid >> 6;
    const long rid = (long)blockIdx.x * 4 + rsub;
    const int bt  = (int)(rid >> 5);
    const int rem = (int)(rid & 31);
    const int h   = rem >> 1;
    const int qk  = rem & 1;

    float* row = qkv + (size_t)bt * F_ + qk * NL_ + h * 64;
    float v = row[lane];

    float ss = v * v;
    ss += __shfl_xor(ss, 1);
    ss += __shfl_xor(ss, 2);
    ss += __shfl_xor(ss, 4);
    ss += __shfl_xor(ss, 8);
    ss += __shfl_xor(ss, 16);
    ss += __shfl_xor(ss, 32);
    const float r = 1.0f / sqrtf(ss * (1.0f / 64.0f) + 1e-6f);
    const float xn = v * r;

    const float other = __shfl_xor(xn, 32);
    const int  i  = lane & 31;
    const int  tt = bt & (T_ - 1);
    const float cv = cosT[tt * DH_ + i];
    const float sv = sinT[tt * DH_ + i];
    float outv;
    if (lane < 32) outv = fmaf(xn, cv,  other * sv);
    else           outv = fmaf(xn, cv, -other * sv);
    row[lane] = outv;
}

// ---------------------------------------------------------------------------
// Split-bf16 MFMA flash attention.  Block = (qb, h, b), 256 threads = 4
// INDEPENDENT waves (no barriers).  Wave w owns q-rows qb*64+w*16 .. +15.
// Per 64-key tile: S = QK^T via 24 mfma (split hi/lo), online softmax on
// the C/D layout, P transposed CD->A-frag through per-wave LDS, PV via 24
// mfma (split).  Q/K/V fragments are loaded straight from global memory.
//   A/B frag: row|col = lane&15, k = (lane>>4)*8+j   (16x16x32 bf16)
//   C/D     : col = lane&15,     row = (lane>>4)*4+reg   [m89]
// ---------------------------------------------------------------------------
__global__ __launch_bounds__(256) void attn_mfma_k(const float* __restrict__ qkv,
                                                   float* __restrict__ Y) {
    __shared__ ushort Plds[4][2][16][88];   // [wave][hi/lo][q][key], stride 88

    const int t    = threadIdx.x;
    const int lane = t & 63;
    const int w    = t >> 6;
    const int g    = lane >> 4;    // 0..3
    const int ln   = lane & 15;    // 0..15
    const int qb   = blockIdx.x;
    const int h    = blockIdx.y;
    const int b    = blockIdx.z;

    const float* base = qkv + (size_t)b * T_ * F_;
    const int q0 = qb * 64 + w * 16;

    // Q A-frags (rows q0+ln, k = kc*32 + g*8 + j), scaled by 1/sqrt(D)
    bf16x8 qh[2], ql[2];
    {
        const float* qrow = base + (size_t)(q0 + ln) * F_ + h * 64;
#pragma unroll
        for (int kc = 0; kc < 2; ++kc) {
            const int d0 = kc * 32 + g * 8;
            const float4 v0 = *(const float4*)(qrow + d0);
            const float4 v1 = *(const float4*)(qrow + d0 + 4);
            split8(v0, v1, 0.125f, qh[kc], ql[kc]);
        }
    }

    f32x4 yacc[4];
    float m[4], l[4];
#pragma unroll
    for (int r = 0; r < 4; ++r) { m[r] = -3.0e38f; l[r] = 0.f; }
#pragma unroll
    for (int n = 0; n < 4; ++n) yacc[n] = (f32x4){0.f, 0.f, 0.f, 0.f};

    for (int kt = 0; kt <= qb; ++kt) {
        const float* kbase = base + (size_t)(kt * 64) * F_ + NL_ + h * 64;

        // ---- S = Q K^T (4 col-tiles of 16 keys) ----
        f32x4 s[4];
#pragma unroll
        for (int jt = 0; jt < 4; ++jt) {
            const float* krow = kbase + (size_t)(jt * 16 + ln) * F_;
            bf16x8 kh[2], kl[2];
#pragma unroll
            for (int kc = 0; kc < 2; ++kc) {
                const int d0 = kc * 32 + g * 8;
                const float4 v0 = *(const float4*)(krow + d0);
                const float4 v1 = *(const float4*)(krow + d0 + 4);
                split8(v0, v1, 1.0f, kh[kc], kl[kc]);
            }
            f32x4 acc = (f32x4){0.f, 0.f, 0.f, 0.f};
            acc = __builtin_amdgcn_mfma_f32_16x16x32_bf16(qh[0], kh[0], acc, 0, 0, 0);
            acc = __builtin_amdgcn_mfma_f32_16x16x32_bf16(qh[0], kl[0], acc, 0, 0, 0);
            acc = __builtin_amdgcn_mfma_f32_16x16x32_bf16(ql[0], kh[0], acc, 0, 0, 0);
            acc = __builtin_amdgcn_mfma_f32_16x16x32_bf16(qh[1], kh[1], acc, 0, 0, 0);
            acc = __builtin_amdgcn_mfma_f32_16x16x32_bf16(qh[1], kl[1], acc, 0, 0, 0);
            acc = __builtin_amdgcn_mfma_f32_16x16x32_bf16(ql[1], kh[1], acc, 0, 0, 0);
            s[jt] = acc;
        }

        // ---- causal mask on diagonal tile ----
        if (kt == qb) {
#pragma unroll
            for (int jt = 0; jt < 4; ++jt) {
                const int gk = kt * 64 + jt * 16 + ln;
#pragma unroll
                for (int r = 0; r < 4; ++r) {
                    if (gk > q0 + g * 4 + r) s[jt][r] = -3.0e38f;
                }
            }
        }

        // ---- online softmax (rows = g*4+r, key cols = ln + 16*jt) ----
#pragma unroll
        for (int r = 0; r < 4; ++r) {
            float tm = fmaxf(fmaxf(s[0][r], s[1][r]), fmaxf(s[2][r], s[3][r]));
            tm = fmaxf(tm, __shfl_xor(tm, 1));
            tm = fmaxf(tm, __shfl_xor(tm, 2));
            tm = fmaxf(tm, __shfl_xor(tm, 4));
            tm = fmaxf(tm, __shfl_xor(tm, 8));
            const float nm = fmaxf(m[r], tm);
            const float co = __expf(m[r] - nm);
            float ps = 0.f;
#pragma unroll
            for (int jt = 0; jt < 4; ++jt) {
                const float p = __expf(s[jt][r] - nm);
                s[jt][r] = p;
                ps += p;
            }
            ps += __shfl_xor(ps, 1);
            ps += __shfl_xor(ps, 2);
            ps += __shfl_xor(ps, 4);
            ps += __shfl_xor(ps, 8);
            l[r] = l[r] * co + ps;
            m[r] = nm;
#pragma unroll
            for (int n = 0; n < 4; ++n) yacc[n][r] *= co;
        }

        // ---- P: CD layout -> split bf16 in LDS ----
#pragma unroll
        for (int jt = 0; jt < 4; ++jt)
#pragma unroll
            for (int r = 0; r < 4; ++r) {
                const float p = s[jt][r];
                const ushort ph = f2bf(p);
                Plds[w][0][g * 4 + r][jt * 16 + ln] = ph;
                Plds[w][1][g * 4 + r][jt * 16 + ln] = f2bf(p - bf2f(ph));
            }
        asm volatile("s_waitcnt lgkmcnt(0)" ::: "memory");   // wave-local fence

        bf16x8 pah[2], pal[2];
#pragma unroll
        for (int kc = 0; kc < 2; ++kc) {
            pah[kc] = *(const bf16x8*)&Plds[w][0][ln][kc * 32 + g * 8];
            pal[kc] = *(const bf16x8*)&Plds[w][1][ln][kc * 32 + g * 8];
        }

        // ---- Y += P V ----
        const float* vbase = base + (size_t)(kt * 64) * F_ + 2 * NL_ + h * 64;
#pragma unroll
        for (int n = 0; n < 4; ++n) {
            const float* vrow = vbase + n * 16 + ln;
#pragma unroll
            for (int kc = 0; kc < 2; ++kc) {
                union { ushort u[8]; bf16x8 v; } VH, VL;
#pragma unroll
                for (int jj = 0; jj < 8; ++jj) {
                    const float vv = vrow[(size_t)(kc * 32 + g * 8 + jj) * F_];
                    const ushort hh = f2bf(vv);
                    VH.u[jj] = hh;
                    VL.u[jj] = f2bf(vv - bf2f(hh));
                }
                yacc[n] = __builtin_amdgcn_mfma_f32_16x16x32_bf16(pah[kc], VH.v, yacc[n], 0, 0, 0);
                yacc[n] = __builtin_amdgcn_mfma_f32_16x16x32_bf16(pah[kc], VL.v, yacc[n], 0, 0, 0);
                yacc[n] = __builtin_amdgcn_mfma_f32_16x16x32_bf16(pal[kc], VH.v, yacc[n], 0, 0, 0);
            }
        }
    }

    // ---- finalize: Y rows q0 + g*4 + r, cols n*16 + ln ----
#pragma unroll
    for (int r = 0; r < 4; ++r) {
        const float inv = 1.0f / l[r];
        const size_t row = (size_t)b * T_ + q0 + g * 4 + r;
#pragma unroll
        for (int n = 0; n < 4; ++n)
            Y[row * NL_ + h * 64 + n * 16 + ln] = yacc[n][r] * inv;
    }
}

// ---------------------------------------------------------------------------
// Workspace/time aliasing (ws known >= 134.74 MB from r2's passing run):
//   ws floats [0,        25165824) : qkv fp32 [GEMM1 -> attn]; later
//                                    woutpack (4.19M u16) @0 + ypack @+8.4MB
//   ws floats [25165824, 33554432) : wqkvpack [pack -> GEMM1]; later y fp32
//   ws floats [33554432, 33685504) : cos/sin tables
//   d_out                          : xpack [pack -> GEMM1], then final out
// ---------------------------------------------------------------------------
extern "C" void kernel_launch(void* const* d_in, const int* in_sizes, int n_in,
                              void* d_out, int out_size, void* d_ws, size_t ws_size,
                              hipStream_t stream) {
    const float* x     = (const float*)d_in[0];
    const float* w_qkv = (const float*)d_in[1];
    const float* w_out = (const float*)d_in[2];
    float* out = (float*)d_out;

    const size_t M = (size_t)B_ * T_;                 // 8192

    float* qkv  = (float*)d_ws;                       // 25,165,824 floats
    float* y    = qkv + M * F_;                       //  8,388,608 floats
    float* cosT = y + M * NL_;
    float* sinT = cosT + (size_t)T_ * DH_;

    ushort* xpack    = (ushort*)d_out;                // 33,554,432 u16 == d_out
    ushort* wqkvpack = (ushort*)y;                    // 12,582,912 u16
    ushort* woutpack = (ushort*)qkv;                  //  4,194,304 u16
    ushort* ypack    = woutpack + (size_t)4194304;    // 16,777,216 u16

    rope_tables_k<<<(T_ * DH_ + 255) / 256, 256, 0, stream>>>(cosT, sinT);

    // ---- QKV projection (bf16x3 MFMA) ----
    pack_split_k<<<dim3(C_ / 32, M / 128), 256, 0, stream>>>(x, xpack, C_, C_ / 32);
    pack_split_k<<<dim3(C_ / 32, F_ / 128), 256, 0, stream>>>(w_qkv, wqkvpack, C_, C_ / 32);
    gemm_bf16x3<<<dim3(F_ / 128, M / 128), 256, 0, stream>>>(
        xpack, wqkvpack, qkv, M / 128, F_ / 128, C_ / 32);

    // ---- norm + rope (in place, fp32) ----
    rmsnorm_rope_k<<<(B_ * T_ * H_ * 2) / 4, 256, 0, stream>>>(qkv, cosT, sinT);

    // ---- attention (split-bf16 MFMA flash) ----
    attn_mfma_k<<<dim3(T_ / 64, H_, B_), 256, 0, stream>>>(qkv, y);

    // ---- output projection (bf16x3 MFMA) ----
    pack_split_k<<<dim3(NL_ / 32, C_ / 128), 256, 0, stream>>>(w_out, woutpack, NL_, NL_ / 32);
    pack_split_k<<<dim3(NL_ / 32, M / 128), 256, 0, stream>>>(y, ypack, NL_, NL_ / 32);
    gemm_bf16x3<<<dim3(C_ / 128, M / 128), 256, 0, stream>>>(
        ypack, woutpack, out, M / 128, C_ / 128, NL_ / 32);
}

// Round 10
// 920.720 us; speedup vs baseline: 2.8460x; 1.2845x over previous
//
#include <hip/hip_runtime.h>
#include <hip/hip_bf16.h>
#include <math.h>

#define B_  4
#define T_  2048
#define C_  2048      // N_EMBD
#define F_  3072      // 3*N_LATENT
#define NL_ 1024      // N_LATENT
#define H_  16
#define D_  64
#define DH_ 32        // half head dim

typedef unsigned int  uint;
typedef unsigned short ushort;
typedef __bf16 bf16x8 __attribute__((ext_vector_type(8)));
typedef float  f32x4  __attribute__((ext_vector_type(4)));

// round-to-nearest-even f32 -> bf16 (finite inputs)
__device__ __forceinline__ ushort f2bf(float f) {
    uint u = __float_as_uint(f);
    u += 0x7FFFu + ((u >> 16) & 1u);
    return (ushort)(u >> 16);
}
__device__ __forceinline__ float bf2f(ushort h) {
    return __uint_as_float(((uint)h) << 16);
}

// split two float4 (8 elems, optional scale) into hi/lo bf16x8 fragments
__device__ __forceinline__ void split8(const float4& v0, const float4& v1,
                                       float scale, bf16x8& hi, bf16x8& lo) {
    union { ushort u[8]; bf16x8 v; } Hh, Ll;
    float vv[8] = {v0.x, v0.y, v0.z, v0.w, v1.x, v1.y, v1.z, v1.w};
#pragma unroll
    for (int j = 0; j < 8; ++j) {
        const float s = scale * vv[j];
        const ushort h = f2bf(s);
        Hh.u[j] = h;
        Ll.u[j] = f2bf(s - bf2f(h));
    }
    hi = Hh.v; lo = Ll.v;
}

// ---------------------------------------------------------------------------
// RoPE tables: cos/sin[t][i], i in [0,32).
// ---------------------------------------------------------------------------
__global__ void rope_tables_k(float* __restrict__ cosT, float* __restrict__ sinT) {
    int idx = blockIdx.x * 256 + threadIdx.x;
    if (idx >= T_ * DH_) return;
    int t = idx >> 5;
    int i = idx & 31;
    float inv = (float)pow(10000.0, -(double)(2 * i) / 64.0);
    float ang = (float)t * inv;
    cosT[idx] = cosf(ang);
    sinT[idx] = sinf(ang);
}

// ---------------------------------------------------------------------------
// Pack fp32 matrix S[R][K] (row-major) into split-bf16 fragment-major tiles.
// [measured-passing r5]
// ---------------------------------------------------------------------------
__global__ __launch_bounds__(256) void pack_split_k(const float* __restrict__ S,
                                                    ushort* __restrict__ P,
                                                    int K, int Ktiles) {
    __shared__ float Ls[128][36];
    const int t  = threadIdx.x;
    const int kt = blockIdx.x;
    const int rt = blockIdx.y;

#pragma unroll
    for (int i = 0; i < 4; ++i) {
        const int f   = t + i * 256;
        const int row = f >> 3;
        const int kc  = (f & 7) * 4;
        const float4 v = *(const float4*)(S + (size_t)(rt * 128 + row) * K + kt * 32 + kc);
        *(float4*)&Ls[row][kc] = v;
    }
    __syncthreads();

    const size_t tb = ((size_t)rt * Ktiles + kt) * 8192;
#pragma unroll
    for (int c = 0; c < 2; ++c) {
        const int ch  = t + c * 256;
        const int row = ((ch >> 6) << 4) + (ch & 15);
        const int k0  = ((ch >> 4) & 3) * 8;
        uint hi[4], lo[4];
#pragma unroll
        for (int jj = 0; jj < 4; ++jj) {
            const float v0 = Ls[row][k0 + jj * 2];
            const float v1 = Ls[row][k0 + jj * 2 + 1];
            const ushort h0 = f2bf(v0), h1 = f2bf(v1);
            const ushort l0 = f2bf(v0 - bf2f(h0)), l1 = f2bf(v1 - bf2f(h1));
            hi[jj] = (uint)h0 | ((uint)h1 << 16);
            lo[jj] = (uint)l0 | ((uint)l1 << 16);
        }
        *(uint4*)(P + tb + (size_t)ch * 8)        = make_uint4(hi[0], hi[1], hi[2], hi[3]);
        *(uint4*)(P + tb + 4096 + (size_t)ch * 8) = make_uint4(lo[0], lo[1], lo[2], lo[3]);
    }
}

// ---------------------------------------------------------------------------
// bf16x3 MFMA GEMM on packed tiles.  [measured-passing r5]
// ---------------------------------------------------------------------------
__global__ __launch_bounds__(256, 2) void gemm_bf16x3(const ushort* __restrict__ Ap,
                                                      const ushort* __restrict__ Bp,
                                                      float* __restrict__ Cc,
                                                      int Mt, int Nt, int Kt) {
    __shared__ ushort Al[8192];   // hi 4096 + lo 4096
    __shared__ ushort Bl[8192];

    const int t    = threadIdx.x;
    const int lane = t & 63;
    const int w    = t >> 6;
    const int wr   = w >> 1, wc = w & 1;
    const int bn   = blockIdx.x, bm = blockIdx.y;

    const ushort* Atiles = Ap + (size_t)bm * Kt * 8192;
    const ushort* Btiles = Bp + (size_t)bn * Kt * 8192;

    const ushort* gbase;
    ushort*       lbase;
    if (w < 2) { gbase = Atiles + w * 4096;       lbase = Al + w * 4096; }
    else       { gbase = Btiles + (w - 2) * 4096; lbase = Bl + (w - 2) * 4096; }

    f32x4 acc[4][4];
#pragma unroll
    for (int i = 0; i < 4; ++i)
#pragma unroll
        for (int j = 0; j < 4; ++j)
            acc[i][j] = (f32x4){0.f, 0.f, 0.f, 0.f};

    for (int kt = 0; kt < Kt; ++kt) {
        const ushort* gsrc = gbase + (size_t)kt * 8192;
#pragma unroll
        for (int i = 0; i < 8; ++i) {
            __builtin_amdgcn_global_load_lds(
                (const __attribute__((address_space(1))) uint*)(gsrc + i * 512 + lane * 8),
                (__attribute__((address_space(3))) uint*)(lbase + i * 512),
                16, 0, 0);
        }
        __syncthreads();

        bf16x8 ah[4], al4[4], bh[4], bl4[4];
#pragma unroll
        for (int i = 0; i < 4; ++i) {
            const int rg = wr * 4 + i;
            ah[i]  = *(const bf16x8*)&Al[rg * 512 + lane * 8];
            al4[i] = *(const bf16x8*)&Al[4096 + rg * 512 + lane * 8];
            const int cg = wc * 4 + i;
            bh[i]  = *(const bf16x8*)&Bl[cg * 512 + lane * 8];
            bl4[i] = *(const bf16x8*)&Bl[4096 + cg * 512 + lane * 8];
        }
#pragma unroll
        for (int i = 0; i < 4; ++i)
#pragma unroll
            for (int j = 0; j < 4; ++j) {
                acc[i][j] = __builtin_amdgcn_mfma_f32_16x16x32_bf16(ah[i],  bh[j],  acc[i][j], 0, 0, 0);
                acc[i][j] = __builtin_amdgcn_mfma_f32_16x16x32_bf16(ah[i],  bl4[j], acc[i][j], 0, 0, 0);
                acc[i][j] = __builtin_amdgcn_mfma_f32_16x16x32_bf16(al4[i], bh[j],  acc[i][j], 0, 0, 0);
            }
        __syncthreads();
    }

    const int N = Nt * 128;
#pragma unroll
    for (int i = 0; i < 4; ++i) {
        const int row0 = bm * 128 + wr * 64 + i * 16 + (lane >> 4) * 4;
#pragma unroll
        for (int j = 0; j < 4; ++j) {
            const int col = bn * 128 + wc * 64 + j * 16 + (lane & 15);
#pragma unroll
            for (int r = 0; r < 4; ++r)
                Cc[(size_t)(row0 + r) * N + col] = acc[i][j][r];
        }
    }
}

// ---------------------------------------------------------------------------
// Fused RMSNorm + RoPE for q and k rows (in place).  [measured-passing r2]
// ---------------------------------------------------------------------------
__global__ __launch_bounds__(256) void rmsnorm_rope_k(float* __restrict__ qkv,
                                                      const float* __restrict__ cosT,
                                                      const float* __restrict__ sinT) {
    const int tid  = threadIdx.x;
    const int lane = tid & 63;
    const int rsub = tid >> 6;
    const long rid = (long)blockIdx.x * 4 + rsub;
    const int bt  = (int)(rid >> 5);
    const int rem = (int)(rid & 31);
    const int h   = rem >> 1;
    const int qk  = rem & 1;

    float* row = qkv + (size_t)bt * F_ + qk * NL_ + h * 64;
    float v = row[lane];

    float ss = v * v;
    ss += __shfl_xor(ss, 1);
    ss += __shfl_xor(ss, 2);
    ss += __shfl_xor(ss, 4);
    ss += __shfl_xor(ss, 8);
    ss += __shfl_xor(ss, 16);
    ss += __shfl_xor(ss, 32);
    const float r = 1.0f / sqrtf(ss * (1.0f / 64.0f) + 1e-6f);
    const float xn = v * r;

    const float other = __shfl_xor(xn, 32);
    const int  i  = lane & 31;
    const int  tt = bt & (T_ - 1);
    const float cv = cosT[tt * DH_ + i];
    const float sv = sinT[tt * DH_ + i];
    float outv;
    if (lane < 32) outv = fmaf(xn, cv,  other * sv);
    else           outv = fmaf(xn, cv, -other * sv);
    row[lane] = outv;
}

// ---------------------------------------------------------------------------
// Split-bf16 MFMA flash attention, v2: COOPERATIVE K/V staging.
// Block = (qb, h, b), 256 threads = 4 waves; wave owns 16 q-rows.
// Per 64-key tile:
//   stage: all 256 threads load K (row-coalesced) + V, split hi/lo ONCE,
//          write to swizzled LDS (K: [key][d], V transposed: [d][key];
//          ushort idx ^= (row&7)<<3  => frag ds_read_b128 conflict-free)
//   T14:   next tile's global loads issue before compute, land in regs
//   compute: QK^T (24 mfma) -> online softmax -> P via per-wave LDS
//            transpose -> PV (24 mfma), all frag reads b128 from LDS.
//   A/B frag: row|col = lane&15, k = (lane>>4)*8+j; C/D: col=lane&15,
//   row=(lane>>4)*4+reg  [m89]
// ---------------------------------------------------------------------------
__global__ __launch_bounds__(256) void attn_mfma2_k(const float* __restrict__ qkv,
                                                    float* __restrict__ Y) {
    __shared__ ushort KlA[2 * 4096];        // [hi/lo][key][d] swizzled
    __shared__ ushort VlA[2 * 4096];        // [hi/lo][d][key] swizzled
    __shared__ ushort Plds[4][2][16][72];   // [wave][hi/lo][q][key]

    const int t    = threadIdx.x;
    const int lane = t & 63;
    const int w    = t >> 6;
    const int g    = lane >> 4;    // 0..3
    const int ln   = lane & 15;    // 0..15
    const int qb   = blockIdx.x;
    const int h    = blockIdx.y;
    const int b    = blockIdx.z;

    const float* base = qkv + (size_t)b * T_ * F_;
    const int q0 = qb * 64 + w * 16;

    // staging thread mapping
    const int kkey = t >> 2;            // K: row (key) 0..63
    const int kd0  = (t & 3) * 16;      // K: dim chunk
    const int vd0  = (t >> 5) * 8;      // V: dim chunk 0..56
    const int vkp  = (t & 31) * 2;      // V: key pair

    // Q A-frags (rows q0+ln, k = kc*32 + g*8 + j), scaled by 1/sqrt(D)
    bf16x8 qh[2], ql[2];
    {
        const float* qrow = base + (size_t)(q0 + ln) * F_ + h * 64;
#pragma unroll
        for (int kc = 0; kc < 2; ++kc) {
            const int d0 = kc * 32 + g * 8;
            const float4 v0 = *(const float4*)(qrow + d0);
            const float4 v1 = *(const float4*)(qrow + d0 + 4);
            split8(v0, v1, 0.125f, qh[kc], ql[kc]);
        }
    }

    f32x4 yacc[4];
    float m[4], l[4];
#pragma unroll
    for (int r = 0; r < 4; ++r) { m[r] = -3.0e38f; l[r] = 0.f; }
#pragma unroll
    for (int n = 0; n < 4; ++n) yacc[n] = (f32x4){0.f, 0.f, 0.f, 0.f};

    // staged tile registers (T14: loads issue one tile ahead)
    float4 kreg[4], vreg[4];
    {
        const float* kr = base + (size_t)kkey * F_ + NL_ + h * 64 + kd0;
        kreg[0] = *(const float4*)(kr);
        kreg[1] = *(const float4*)(kr + 4);
        kreg[2] = *(const float4*)(kr + 8);
        kreg[3] = *(const float4*)(kr + 12);
        const float* vr = base + (size_t)vkp * F_ + 2 * NL_ + h * 64 + vd0;
        vreg[0] = *(const float4*)(vr);
        vreg[1] = *(const float4*)(vr + 4);
        vreg[2] = *(const float4*)(vr + F_);
        vreg[3] = *(const float4*)(vr + F_ + 4);
    }

    for (int kt = 0; kt <= qb; ++kt) {
        __syncthreads();   // previous tile's frag reads done; LDS writable

        // ---- split & write K: [key][d], idx ^= (key&7)<<3 ----
        {
            const float kf[16] = {kreg[0].x, kreg[0].y, kreg[0].z, kreg[0].w,
                                  kreg[1].x, kreg[1].y, kreg[1].z, kreg[1].w,
                                  kreg[2].x, kreg[2].y, kreg[2].z, kreg[2].w,
                                  kreg[3].x, kreg[3].y, kreg[3].z, kreg[3].w};
#pragma unroll
            for (int u = 0; u < 8; ++u) {
                const float a = kf[2 * u], c = kf[2 * u + 1];
                const ushort ha = f2bf(a), hc = f2bf(c);
                const ushort la = f2bf(a - bf2f(ha)), lc = f2bf(c - bf2f(hc));
                const int d = kd0 + 2 * u;
                const uint idx = (uint)((kkey << 6) + d) ^ (uint)((kkey & 7) << 3);
                *(uint*)&KlA[idx]        = (uint)ha | ((uint)hc << 16);
                *(uint*)&KlA[4096 + idx] = (uint)la | ((uint)lc << 16);
            }
        }
        // ---- split & write V transposed: [d][key], idx ^= (d&7)<<3 ----
        {
            const float v0f[8] = {vreg[0].x, vreg[0].y, vreg[0].z, vreg[0].w,
                                  vreg[1].x, vreg[1].y, vreg[1].z, vreg[1].w};
            const float v1f[8] = {vreg[2].x, vreg[2].y, vreg[2].z, vreg[2].w,
                                  vreg[3].x, vreg[3].y, vreg[3].z, vreg[3].w};
#pragma unroll
            for (int u = 0; u < 8; ++u) {
                const float a = v0f[u], c = v1f[u];      // keys vkp, vkp+1 @ dim d
                const ushort ha = f2bf(a), hc = f2bf(c);
                const ushort la = f2bf(a - bf2f(ha)), lc = f2bf(c - bf2f(hc));
                const int d = vd0 + u;
                const uint idx = (uint)((d << 6) + vkp) ^ (uint)((d & 7) << 3);
                *(uint*)&VlA[idx]        = (uint)ha | ((uint)hc << 16);
                *(uint*)&VlA[4096 + idx] = (uint)la | ((uint)lc << 16);
            }
        }

        // ---- T14: issue next tile's global loads into regs ----
        if (kt < qb) {
            const float* kr = base + (size_t)((kt + 1) * 64 + kkey) * F_ + NL_ + h * 64 + kd0;
            kreg[0] = *(const float4*)(kr);
            kreg[1] = *(const float4*)(kr + 4);
            kreg[2] = *(const float4*)(kr + 8);
            kreg[3] = *(const float4*)(kr + 12);
            const float* vr = base + (size_t)((kt + 1) * 64 + vkp) * F_ + 2 * NL_ + h * 64 + vd0;
            vreg[0] = *(const float4*)(vr);
            vreg[1] = *(const float4*)(vr + 4);
            vreg[2] = *(const float4*)(vr + F_);
            vreg[3] = *(const float4*)(vr + F_ + 4);
        }

        __syncthreads();   // staged tile visible to all waves

        // ---- S = Q K^T (4 col-tiles of 16 keys) ----
        f32x4 s[4];
#pragma unroll
        for (int jt = 0; jt < 4; ++jt) {
            const int key = jt * 16 + ln;
            f32x4 acc = (f32x4){0.f, 0.f, 0.f, 0.f};
#pragma unroll
            for (int kc = 0; kc < 2; ++kc) {
                const uint kidx = (uint)((key << 6) + kc * 32 + g * 8) ^ (uint)((key & 7) << 3);
                const bf16x8 kh = *(const bf16x8*)&KlA[kidx];
                const bf16x8 kl = *(const bf16x8*)&KlA[4096 + kidx];
                acc = __builtin_amdgcn_mfma_f32_16x16x32_bf16(qh[kc], kh, acc, 0, 0, 0);
                acc = __builtin_amdgcn_mfma_f32_16x16x32_bf16(qh[kc], kl, acc, 0, 0, 0);
                acc = __builtin_amdgcn_mfma_f32_16x16x32_bf16(ql[kc], kh, acc, 0, 0, 0);
            }
            s[jt] = acc;
        }

        // ---- causal mask on diagonal tile ----
        if (kt == qb) {
#pragma unroll
            for (int jt = 0; jt < 4; ++jt) {
                const int gk = kt * 64 + jt * 16 + ln;
#pragma unroll
                for (int r = 0; r < 4; ++r) {
                    if (gk > q0 + g * 4 + r) s[jt][r] = -3.0e38f;
                }
            }
        }

        // ---- online softmax (rows = g*4+r, key cols = ln + 16*jt) ----
#pragma unroll
        for (int r = 0; r < 4; ++r) {
            float tm = fmaxf(fmaxf(s[0][r], s[1][r]), fmaxf(s[2][r], s[3][r]));
            tm = fmaxf(tm, __shfl_xor(tm, 1));
            tm = fmaxf(tm, __shfl_xor(tm, 2));
            tm = fmaxf(tm, __shfl_xor(tm, 4));
            tm = fmaxf(tm, __shfl_xor(tm, 8));
            const float nm = fmaxf(m[r], tm);
            const float co = __expf(m[r] - nm);
            float ps = 0.f;
#pragma unroll
            for (int jt = 0; jt < 4; ++jt) {
                const float p = __expf(s[jt][r] - nm);
                s[jt][r] = p;
                ps += p;
            }
            ps += __shfl_xor(ps, 1);
            ps += __shfl_xor(ps, 2);
            ps += __shfl_xor(ps, 4);
            ps += __shfl_xor(ps, 8);
            l[r] = l[r] * co + ps;
            m[r] = nm;
#pragma unroll
            for (int n = 0; n < 4; ++n) yacc[n][r] *= co;
        }

        // ---- P: CD layout -> split bf16 in per-wave LDS (transpose) ----
#pragma unroll
        for (int jt = 0; jt < 4; ++jt)
#pragma unroll
            for (int r = 0; r < 4; ++r) {
                const float p = s[jt][r];
                const ushort ph = f2bf(p);
                Plds[w][0][g * 4 + r][jt * 16 + ln] = ph;
                Plds[w][1][g * 4 + r][jt * 16 + ln] = f2bf(p - bf2f(ph));
            }
        asm volatile("s_waitcnt lgkmcnt(0)" ::: "memory");   // wave-local fence

        bf16x8 pah[2], pal[2];
#pragma unroll
        for (int kc = 0; kc < 2; ++kc) {
            pah[kc] = *(const bf16x8*)&Plds[w][0][ln][kc * 32 + g * 8];
            pal[kc] = *(const bf16x8*)&Plds[w][1][ln][kc * 32 + g * 8];
        }

        // ---- Y += P V (V frags from transposed swizzled LDS) ----
#pragma unroll
        for (int n = 0; n < 4; ++n) {
            const int d = n * 16 + ln;
#pragma unroll
            for (int kc = 0; kc < 2; ++kc) {
                const uint vidx = (uint)((d << 6) + kc * 32 + g * 8) ^ (uint)((d & 7) << 3);
                const bf16x8 vh = *(const bf16x8*)&VlA[vidx];
                const bf16x8 vl = *(const bf16x8*)&VlA[4096 + vidx];
                yacc[n] = __builtin_amdgcn_mfma_f32_16x16x32_bf16(pah[kc], vh, yacc[n], 0, 0, 0);
                yacc[n] = __builtin_amdgcn_mfma_f32_16x16x32_bf16(pah[kc], vl, yacc[n], 0, 0, 0);
                yacc[n] = __builtin_amdgcn_mfma_f32_16x16x32_bf16(pal[kc], vh, yacc[n], 0, 0, 0);
            }
        }
    }

    // ---- finalize: Y rows q0 + g*4 + r, cols n*16 + ln ----
#pragma unroll
    for (int r = 0; r < 4; ++r) {
        const float inv = 1.0f / l[r];
        const size_t row = (size_t)b * T_ + q0 + g * 4 + r;
#pragma unroll
        for (int n = 0; n < 4; ++n)
            Y[row * NL_ + h * 64 + n * 16 + ln] = yacc[n][r] * inv;
    }
}

// ---------------------------------------------------------------------------
// Workspace/time aliasing (ws >= 134.74 MB, verified r2/r5):
//   ws floats [0,        25165824) : qkv fp32 [GEMM1 -> attn]; later
//                                    woutpack (4.19M u16) @0 + ypack @+8.4MB
//   ws floats [25165824, 33554432) : wqkvpack [pack -> GEMM1]; later y fp32
//   ws floats [33554432, 33685504) : cos/sin tables
//   d_out                          : xpack [pack -> GEMM1], then final out
// ---------------------------------------------------------------------------
extern "C" void kernel_launch(void* const* d_in, const int* in_sizes, int n_in,
                              void* d_out, int out_size, void* d_ws, size_t ws_size,
                              hipStream_t stream) {
    const float* x     = (const float*)d_in[0];
    const float* w_qkv = (const float*)d_in[1];
    const float* w_out = (const float*)d_in[2];
    float* out = (float*)d_out;

    const size_t M = (size_t)B_ * T_;                 // 8192

    float* qkv  = (float*)d_ws;                       // 25,165,824 floats
    float* y    = qkv + M * F_;                       //  8,388,608 floats
    float* cosT = y + M * NL_;
    float* sinT = cosT + (size_t)T_ * DH_;

    ushort* xpack    = (ushort*)d_out;                // 33,554,432 u16 == d_out
    ushort* wqkvpack = (ushort*)y;                    // 12,582,912 u16
    ushort* woutpack = (ushort*)qkv;                  //  4,194,304 u16
    ushort* ypack    = woutpack + (size_t)4194304;    // 16,777,216 u16

    rope_tables_k<<<(T_ * DH_ + 255) / 256, 256, 0, stream>>>(cosT, sinT);

    // ---- QKV projection (bf16x3 MFMA) ----
    pack_split_k<<<dim3(C_ / 32, M / 128), 256, 0, stream>>>(x, xpack, C_, C_ / 32);
    pack_split_k<<<dim3(C_ / 32, F_ / 128), 256, 0, stream>>>(w_qkv, wqkvpack, C_, C_ / 32);
    gemm_bf16x3<<<dim3(F_ / 128, M / 128), 256, 0, stream>>>(
        xpack, wqkvpack, qkv, M / 128, F_ / 128, C_ / 32);

    // ---- norm + rope (in place, fp32) ----
    rmsnorm_rope_k<<<(B_ * T_ * H_ * 2) / 4, 256, 0, stream>>>(qkv, cosT, sinT);

    // ---- attention (split-bf16 MFMA flash, cooperative staging) ----
    attn_mfma2_k<<<dim3(T_ / 64, H_, B_), 256, 0, stream>>>(qkv, y);

    // ---- output projection (bf16x3 MFMA) ----
    pack_split_k<<<dim3(NL_ / 32, C_ / 128), 256, 0, stream>>>(w_out, woutpack, NL_, NL_ / 32);
    pack_split_k<<<dim3(NL_ / 32, M / 128), 256, 0, stream>>>(y, ypack, NL_, NL_ / 32);
    gemm_bf16x3<<<dim3(C_ / 128, M / 128), 256, 0, stream>>>(
        ypack, woutpack, out, M / 128, C_ / 128, NL_ / 32);
}